// Round 2
// baseline (236.693 us; speedup 1.0000x reference)
//
#include <hip/hip_runtime.h>
#include <float.h>

#define D 64
#define K 512
#define HW 1024
#define DHW (D * HW)
#define N_PTS 65536
#define OUT_ELEMS (64 * D * HW)     /* 4,194,304 */
#define LOSS_OFF OUT_ELEMS
#define IDX_OFF (OUT_ELEMS + 1)

// ---------------------------------------------------------------------------
// numpy pairwise-sum (n=64) replication helper: 8 accumulators over squares,
// combined ((r0+r1)+(r2+r3))+((r4+r5)+(r6+r7)), all adds/muls un-contracted.
// ---------------------------------------------------------------------------
__device__ __forceinline__ float np_sumsq64(const float* v) {
    float r[8];
#pragma unroll
    for (int j = 0; j < 8; ++j) r[j] = __fmul_rn(v[j], v[j]);
#pragma unroll
    for (int i = 8; i < D; i += 8) {
#pragma unroll
        for (int j = 0; j < 8; ++j)
            r[j] = __fadd_rn(r[j], __fmul_rn(v[i + j], v[i + j]));
    }
    return __fadd_rn(
        __fadd_rn(__fadd_rn(r[0], r[1]), __fadd_rn(r[2], r[3])),
        __fadd_rn(__fadd_rn(r[4], r[5]), __fadd_rn(r[6], r[7])));
}

// ---------------------------------------------------------------------------
// Kernel 1: ||e_k||^2 in numpy pairwise order -> ws
// ---------------------------------------------------------------------------
__global__ void vq_e2_kernel(const float* __restrict__ cb,
                             float* __restrict__ e2) {
    int k = blockIdx.x * blockDim.x + threadIdx.x;
    if (k < K) {
        float row[D];
#pragma unroll
        for (int d = 0; d < D; ++d) row[d] = cb[k * D + d];
        e2[k] = np_sumsq64(row);
    }
}

// ---------------------------------------------------------------------------
// Kernel 2: main VQ. One lane = one spatial point (coalesced z/out).
// dist_k = fl( fl(A + B_k) - fl(2*M_k) )  -- replicates numpy's rounding so
// quantized ties resolve identically; strict < ascending = first-index argmin.
// ---------------------------------------------------------------------------
__global__ __launch_bounds__(256) void vq_main_kernel(
        const float* __restrict__ z, const float* __restrict__ cb,
        const float* __restrict__ e2, float* __restrict__ out,
        float* __restrict__ partial) {
    const int lane = threadIdx.x & 63;
    const int wave = threadIdx.x >> 6;
    const int n    = blockIdx.x * 256 + threadIdx.x;   // point id
    const int b    = n >> 10;                          // image (HW = 1024)
    const int hw   = n & 1023;

    // Load this lane's feature vector x[0..63]; lane-coalesced per d.
    const float* zp = z + b * DHW + hw;
    float x[D];
#pragma unroll
    for (int d = 0; d < D; ++d) x[d] = zp[d * HW];

    const float A = np_sumsq64(x);   // numpy-order ||x||^2

    float best = FLT_MAX;
    int   bidx = 0;
    for (int kk = 0; kk < K; kk += 8) {
        float acc[8];
#pragma unroll
        for (int j = 0; j < 8; ++j) acc[j] = 0.f;
#pragma unroll
        for (int d = 0; d < D; ++d) {
#pragma unroll
            for (int j = 0; j < 8; ++j) {
                // M_j += x[d] * e[kk+j][d]; cb operand is wave-uniform (s_load).
                acc[j] = __builtin_fmaf(x[d], cb[(kk + j) * D + d], acc[j]);
            }
        }
#pragma unroll
        for (int j = 0; j < 8; ++j) {
            // 2*acc exact (power of two); adds in numpy's association.
            float dist = __fsub_rn(__fadd_rn(A, e2[kk + j]), 2.0f * acc[j]);
            if (dist < best) { best = dist; bidx = kk + j; }
        }
    }

    // Epilogue: gather chosen code row, replicate out = fl(x + fl(q - x)),
    // accumulate loss partials from diff = fl(q - x).
    const float4* qrow = reinterpret_cast<const float4*>(cb + bidx * D);
    float* op = out + b * DHW + hw;
    float lsum = 0.f;
#pragma unroll
    for (int dd = 0; dd < D / 4; ++dd) {
        float4 q4 = qrow[dd];
        float qv[4] = {q4.x, q4.y, q4.z, q4.w};
#pragma unroll
        for (int j = 0; j < 4; ++j) {
            const int d = dd * 4 + j;
            float diff = __fsub_rn(qv[j], x[d]);
            lsum = __builtin_fmaf(diff, diff, lsum);
            op[d * HW] = __fadd_rn(x[d], diff);
        }
    }

    // idx output (stored as float in the flat f32 output buffer)
    out[IDX_OFF + n] = (float)bidx;

    // Deterministic loss partials: wave shuffle reduce -> LDS -> per-block.
#pragma unroll
    for (int off = 32; off > 0; off >>= 1) lsum += __shfl_down(lsum, off);
    __shared__ float wsum[4];
    if (lane == 0) wsum[wave] = lsum;
    __syncthreads();
    if (threadIdx.x == 0)
        partial[blockIdx.x] = wsum[0] + wsum[1] + wsum[2] + wsum[3];
}

// ---------------------------------------------------------------------------
// Kernel 3: reduce 256 block partials -> loss = 1.25 * MSE
// ---------------------------------------------------------------------------
__global__ void vq_loss_kernel(const float* __restrict__ partial,
                               float* __restrict__ out) {
    __shared__ float sh[256];
    sh[threadIdx.x] = partial[threadIdx.x];
    __syncthreads();
    for (int off = 128; off > 0; off >>= 1) {
        if (threadIdx.x < off) sh[threadIdx.x] += sh[threadIdx.x + off];
        __syncthreads();
    }
    if (threadIdx.x == 0)
        out[LOSS_OFF] = 1.25f * sh[0] / (float)OUT_ELEMS;
}

extern "C" void kernel_launch(void* const* d_in, const int* in_sizes, int n_in,
                              void* d_out, int out_size, void* d_ws,
                              size_t ws_size, hipStream_t stream) {
    const float* z  = (const float*)d_in[0];   // [64, 64, 32, 32] f32
    const float* cb = (const float*)d_in[1];   // [512, 64] f32
    float* out = (float*)d_out;
    float* wsf = (float*)d_ws;
    float* e2      = wsf;          // 512 floats
    float* partial = wsf + K;      // 256 floats

    vq_e2_kernel<<<(K + 255) / 256, 256, 0, stream>>>(cb, e2);
    vq_main_kernel<<<N_PTS / 256, 256, 0, stream>>>(z, cb, e2, out, partial);
    vq_loss_kernel<<<1, 256, 0, stream>>>(partial, out);
}

// Round 3
// 233.011 us; speedup vs baseline: 1.0158x; 1.0158x over previous
//
#include <hip/hip_runtime.h>
#include <float.h>

#define D 64
#define K 512
#define HW 1024
#define DHW (D * HW)
#define N_PTS 65536
#define OUT_ELEMS (64 * D * HW)     /* 4,194,304 */
#define LOSS_OFF OUT_ELEMS
#define IDX_OFF (OUT_ELEMS + 1)

// ---------------------------------------------------------------------------
// numpy pairwise-sum (n=64) replication helper: 8 accumulators over squares,
// combined ((r0+r1)+(r2+r3))+((r4+r5)+(r6+r7)), all adds/muls un-contracted.
// ---------------------------------------------------------------------------
__device__ __forceinline__ float np_sumsq64(const float* v) {
    float r[8];
#pragma unroll
    for (int j = 0; j < 8; ++j) r[j] = __fmul_rn(v[j], v[j]);
#pragma unroll
    for (int i = 8; i < D; i += 8) {
#pragma unroll
        for (int j = 0; j < 8; ++j)
            r[j] = __fadd_rn(r[j], __fmul_rn(v[i + j], v[i + j]));
    }
    return __fadd_rn(
        __fadd_rn(__fadd_rn(r[0], r[1]), __fadd_rn(r[2], r[3])),
        __fadd_rn(__fadd_rn(r[4], r[5]), __fadd_rn(r[6], r[7])));
}

// ---------------------------------------------------------------------------
// Kernel 1: ||e_k||^2 in numpy pairwise order -> ws
// ---------------------------------------------------------------------------
__global__ void vq_e2_kernel(const float* __restrict__ cb,
                             float* __restrict__ e2) {
    int k = blockIdx.x * blockDim.x + threadIdx.x;
    if (k < K) {
        float row[D];
#pragma unroll
        for (int d = 0; d < D; ++d) row[d] = cb[k * D + d];
        e2[k] = np_sumsq64(row);
    }
}

// ---------------------------------------------------------------------------
// Kernel 2: main VQ. One lane = one spatial point (coalesced z/out).
// __launch_bounds__(256, 1): grid is 1024 waves on 1024 SIMDs, so capping
// VGPRs for >1 wave/SIMD occupancy is pure loss — x[64] MUST stay in VGPRs
// (round 2 post-mortem: VGPR_Count=56 => x[] spilled to scratch, 8.7x slow).
// ---------------------------------------------------------------------------
__global__ __launch_bounds__(256, 1) void vq_main_kernel(
        const float* __restrict__ z, const float* __restrict__ cb,
        const float* __restrict__ e2, float* __restrict__ out,
        float* __restrict__ partial) {
    const int lane = threadIdx.x & 63;
    const int wave = threadIdx.x >> 6;
    const int n    = blockIdx.x * 256 + threadIdx.x;   // point id
    const int b    = n >> 10;                          // image (HW = 1024)
    const int hw   = n & 1023;

    // Load this lane's feature vector x[0..63]; lane-coalesced per d.
    const float* zp = z + b * DHW + hw;
    float x[D];
#pragma unroll
    for (int d = 0; d < D; ++d) x[d] = zp[d * HW];

    const float A = np_sumsq64(x);   // numpy-order ||x||^2

    float best = FLT_MAX;
    int   bidx = 0;
    for (int kk = 0; kk < K; kk += 8) {
        // Preload this batch's e2 (wave-uniform scalar loads; also gives the
        // scheduler an early anchor for the batch's cb s_loads).
        float dbias[8];
#pragma unroll
        for (int j = 0; j < 8; ++j) dbias[j] = __fadd_rn(A, e2[kk + j]);

        float acc[8];
#pragma unroll
        for (int j = 0; j < 8; ++j) acc[j] = 0.f;
#pragma unroll
        for (int d = 0; d < D; ++d) {
#pragma unroll
            for (int j = 0; j < 8; ++j) {
                // M_j += x[d] * e[kk+j][d]; cb operand is wave-uniform (s_load).
                acc[j] = __builtin_fmaf(x[d], cb[(kk + j) * D + d], acc[j]);
            }
        }
#pragma unroll
        for (int j = 0; j < 8; ++j) {
            // 2*acc exact (power of two); adds in numpy's association:
            // dist = fl( fl(A + B_k) - fl(2*M_k) )
            float dist = __fsub_rn(dbias[j], 2.0f * acc[j]);
            if (dist < best) { best = dist; bidx = kk + j; }
        }
    }

    // Epilogue: gather chosen code row, replicate out = fl(x + fl(q - x)),
    // accumulate loss partials from diff = fl(q - x).
    const float4* qrow = reinterpret_cast<const float4*>(cb + bidx * D);
    float* op = out + b * DHW + hw;
    float lsum = 0.f;
#pragma unroll
    for (int dd = 0; dd < D / 4; ++dd) {
        float4 q4 = qrow[dd];
        float qv[4] = {q4.x, q4.y, q4.z, q4.w};
#pragma unroll
        for (int j = 0; j < 4; ++j) {
            const int d = dd * 4 + j;
            float diff = __fsub_rn(qv[j], x[d]);
            lsum = __builtin_fmaf(diff, diff, lsum);
            op[d * HW] = __fadd_rn(x[d], diff);
        }
    }

    // idx output (stored as float in the flat f32 output buffer)
    out[IDX_OFF + n] = (float)bidx;

    // Deterministic loss partials: wave shuffle reduce -> LDS -> per-block.
#pragma unroll
    for (int off = 32; off > 0; off >>= 1) lsum += __shfl_down(lsum, off);
    __shared__ float wsum[4];
    if (lane == 0) wsum[wave] = lsum;
    __syncthreads();
    if (threadIdx.x == 0)
        partial[blockIdx.x] = wsum[0] + wsum[1] + wsum[2] + wsum[3];
}

// ---------------------------------------------------------------------------
// Kernel 3: reduce 256 block partials -> loss = 1.25 * MSE
// ---------------------------------------------------------------------------
__global__ void vq_loss_kernel(const float* __restrict__ partial,
                               float* __restrict__ out) {
    __shared__ float sh[256];
    sh[threadIdx.x] = partial[threadIdx.x];
    __syncthreads();
    for (int off = 128; off > 0; off >>= 1) {
        if (threadIdx.x < off) sh[threadIdx.x] += sh[threadIdx.x + off];
        __syncthreads();
    }
    if (threadIdx.x == 0)
        out[LOSS_OFF] = 1.25f * sh[0] / (float)OUT_ELEMS;
}

extern "C" void kernel_launch(void* const* d_in, const int* in_sizes, int n_in,
                              void* d_out, int out_size, void* d_ws,
                              size_t ws_size, hipStream_t stream) {
    const float* z  = (const float*)d_in[0];   // [64, 64, 32, 32] f32
    const float* cb = (const float*)d_in[1];   // [512, 64] f32
    float* out = (float*)d_out;
    float* wsf = (float*)d_ws;
    float* e2      = wsf;          // 512 floats
    float* partial = wsf + K;      // 256 floats

    vq_e2_kernel<<<(K + 255) / 256, 256, 0, stream>>>(cb, e2);
    vq_main_kernel<<<N_PTS / 256, 256, 0, stream>>>(z, cb, e2, out, partial);
    vq_loss_kernel<<<1, 256, 0, stream>>>(partial, out);
}